// Round 5
// baseline (495.341 us; speedup 1.0000x reference)
//
#include <hip/hip_runtime.h>
#include <hip/hip_bf16.h>
#include <math.h>

#define D_MODEL 1024
#define D_FF    4096
#define N_HEADS 16
#define SEQ     1000
#define BATCH   8
#define M_TOK   (BATCH * SEQ)   // 8000 tokens

typedef __bf16 bf16x8_t __attribute__((ext_vector_type(8)));
typedef short  short8_t __attribute__((ext_vector_type(8)));
typedef float  f32x4_t  __attribute__((ext_vector_type(4)));

__device__ __forceinline__ f32x4_t mfma_bf16(short8_t a, short8_t b, f32x4_t c) {
    return __builtin_amdgcn_mfma_f32_16x16x32_bf16(
        __builtin_bit_cast(bf16x8_t, a), __builtin_bit_cast(bf16x8_t, b), c, 0, 0, 0);
}

// fp32 -> bf16 round-to-nearest-even
__device__ __forceinline__ unsigned short f2bf(float f) {
    union { float f; unsigned u; } x; x.f = f;
    unsigned r = (x.u + 0x7fffu + ((x.u >> 16) & 1u)) >> 16;
    return (unsigned short)r;
}

// fast GELU (tanh form): max abs dev vs exact erf-GELU ~3e-4, below bf16 rounding
__device__ __forceinline__ float gelu_fast(float v) {
    float z = 1.5957691216f * v * fmaf(0.044715f, v * v, 1.0f);
    float e = __expf(-z);                       // v_exp_f32
    return v * __builtin_amdgcn_rcpf(1.0f + e); // v_rcp_f32
}

// async global(16B/lane) -> LDS (wave-uniform base + lane*16)
__device__ __forceinline__ void gload_lds16(const void* g, void* l) {
    __builtin_amdgcn_global_load_lds(
        (const __attribute__((address_space(1))) unsigned int*)g,
        (__attribute__((address_space(3))) unsigned int*)l, 16, 0, 0);
}

// ---------------------------------------------------------------------------
// Prep: all 6 weight transposes (fp32 [K][N] -> bf16 [N][K]) + LN1, one launch.
// ---------------------------------------------------------------------------
__global__ __launch_bounds__(256) void prep_kernel(
    const float* __restrict__ wq, const float* __restrict__ wk,
    const float* __restrict__ wv, const float* __restrict__ wo,
    const float* __restrict__ w1, const float* __restrict__ w2,
    unsigned short* __restrict__ wqt, unsigned short* __restrict__ wkt,
    unsigned short* __restrict__ wvt, unsigned short* __restrict__ wot,
    unsigned short* __restrict__ w1t, unsigned short* __restrict__ w2t,
    const float* __restrict__ x, const float* __restrict__ g1,
    const float* __restrict__ beta1, unsigned short* __restrict__ h1) {
    int id = blockIdx.x;
    __shared__ float tile[32][33];
    __shared__ float red[8];
    if (id >= 12288) {
        // ---- LayerNorm row ----
        int row = id - 12288, tid = threadIdx.x;
        const float4 v = ((const float4*)(x + (size_t)row * D_MODEL))[tid];
        float s  = v.x + v.y + v.z + v.w;
        float s2 = v.x * v.x + v.y * v.y + v.z * v.z + v.w * v.w;
#pragma unroll
        for (int o = 32; o > 0; o >>= 1) { s += __shfl_xor(s, o, 64); s2 += __shfl_xor(s2, o, 64); }
        int wave = tid >> 6, lane = tid & 63;
        if (lane == 0) { red[wave] = s; red[wave + 4] = s2; }
        __syncthreads();
        s  = red[0] + red[1] + red[2] + red[3];
        s2 = red[4] + red[5] + red[6] + red[7];
        float mean = s * (1.0f / D_MODEL);
        float var  = s2 * (1.0f / D_MODEL) - mean * mean;
        float rstd = rsqrtf(var + 1e-5f);
        float4 gg = ((const float4*)g1)[tid];
        float4 bb = ((const float4*)beta1)[tid];
        ushort4 o4;
        o4.x = f2bf((v.x - mean) * rstd * gg.x + bb.x);
        o4.y = f2bf((v.y - mean) * rstd * gg.y + bb.y);
        o4.z = f2bf((v.z - mean) * rstd * gg.z + bb.z);
        o4.w = f2bf((v.w - mean) * rstd * gg.w + bb.w);
        ((ushort4*)(h1 + (size_t)row * D_MODEL))[tid] = o4;
        return;
    }
    // ---- weight transpose ----
    const float* w; unsigned short* wt; int Kd, Nd, bx, by;
    if (id < 4096) {
        int z = id >> 10, t = id & 1023;
        w  = z == 0 ? wq  : z == 1 ? wk  : z == 2 ? wv  : wo;
        wt = z == 0 ? wqt : z == 1 ? wkt : z == 2 ? wvt : wot;
        Kd = 1024; Nd = 1024; bx = t & 31; by = t >> 5;
    } else if (id < 8192) {
        int t = id - 4096;
        w = w1; wt = w1t; Kd = 1024; Nd = 4096; bx = t & 127; by = t >> 7;
    } else {
        int t = id - 8192;
        w = w2; wt = w2t; Kd = 4096; Nd = 1024; bx = t & 31; by = t >> 5;
    }
    int n0 = bx * 32, k0 = by * 32;
    int tx = threadIdx.x & 31, ty = threadIdx.x >> 5;  // 32 x 8
#pragma unroll
    for (int i = 0; i < 4; ++i)
        tile[ty + i * 8][tx] = w[(size_t)(k0 + ty + i * 8) * Nd + n0 + tx];
    __syncthreads();
#pragma unroll
    for (int i = 0; i < 4; ++i)
        wt[(size_t)(n0 + ty + i * 8) * Kd + k0 + tx] = f2bf(tile[tx][ty + i * 8]);
}

// ---------------------------------------------------------------------------
// V transpose: v bf16 [b*1000+s][h*64+dk] -> vt bf16 [b][h*64+dk][1024] (s pad 0)
// ---------------------------------------------------------------------------
__global__ __launch_bounds__(256) void vtrans_kernel(const unsigned short* __restrict__ v,
                                                     unsigned short* __restrict__ vt) {
    __shared__ unsigned short tile[32][33];
    int b = blockIdx.z;
    int c0 = blockIdx.x * 32, s0 = blockIdx.y * 32;
    int tx = threadIdx.x, ty = threadIdx.y;
#pragma unroll
    for (int i = 0; i < 4; ++i) {
        int s = s0 + ty + i * 8;
        unsigned short val = 0;
        if (s < SEQ) val = v[((size_t)b * SEQ + s) * D_MODEL + c0 + tx];
        tile[ty + i * 8][tx] = val;
    }
    __syncthreads();
#pragma unroll
    for (int i = 0; i < 4; ++i) {
        int c = c0 + ty + i * 8;
        vt[((size_t)b * D_MODEL + c) * 1024 + s0 + tx] = tile[tx][ty + i * 8];
    }
}

// ---------------------------------------------------------------------------
// LayerNorm: x fp32 [row][1024] -> out bf16, 1 block per row
// ---------------------------------------------------------------------------
__global__ __launch_bounds__(256) void ln_kernel(const float* __restrict__ x,
                                                 const float* __restrict__ g,
                                                 const float* __restrict__ beta,
                                                 unsigned short* __restrict__ out) {
    int row = blockIdx.x, tid = threadIdx.x;
    const float4 v = ((const float4*)(x + (size_t)row * D_MODEL))[tid];
    float s  = v.x + v.y + v.z + v.w;
    float s2 = v.x * v.x + v.y * v.y + v.z * v.z + v.w * v.w;
#pragma unroll
    for (int o = 32; o > 0; o >>= 1) { s += __shfl_xor(s, o, 64); s2 += __shfl_xor(s2, o, 64); }
    __shared__ float red[8];
    int wave = tid >> 6, lane = tid & 63;
    if (lane == 0) { red[wave] = s; red[wave + 4] = s2; }
    __syncthreads();
    s  = red[0] + red[1] + red[2] + red[3];
    s2 = red[4] + red[5] + red[6] + red[7];
    float mean = s * (1.0f / D_MODEL);
    float var  = s2 * (1.0f / D_MODEL) - mean * mean;
    float rstd = rsqrtf(var + 1e-5f);
    float4 gg = ((const float4*)g)[tid];
    float4 bb = ((const float4*)beta)[tid];
    ushort4 o4;
    o4.x = f2bf((v.x - mean) * rstd * gg.x + bb.x);
    o4.y = f2bf((v.y - mean) * rstd * gg.y + bb.y);
    o4.z = f2bf((v.z - mean) * rstd * gg.z + bb.z);
    o4.w = f2bf((v.w - mean) * rstd * gg.w + bb.w);
    ((ushort4*)(out + (size_t)row * D_MODEL))[tid] = o4;
}

enum { EPI_BF16 = 0, EPI_GELU = 1, EPI_RES_F32 = 2 };

// ---------------------------------------------------------------------------
// gemm128s: 128x256 tile, 8 waves (2M x 4N), per-wave 64x64 (acc[4][4]),
// BK=32, 4-slot ring (96 KiB), prefetch distance 3 — PLUS software-pipelined
// fragment reads (the R5 change):
//
//   iter t: vmcnt(3) [proves t+1 landed]; barrier;
//           issue 8 ds_read_b128 for tile t+1 -> ALTERNATE reg set;
//           stage(t+3);
//           lgkmcnt(8) [drains tile t's reads; t+1's 8 stay in flight];
//           sched_barrier(0)  [rule #18: stop MFMA hoisting past the asm];
//           setprio(1); 16 MFMA on CURRENT set; setprio(0).
//
// Tile t+1's ds_read issue+latency now hides under tile t's MFMA cluster +
// the next barrier wait, instead of sitting on the critical path after each
// barrier (R2/R4 structure: barrier->reads->wait->MFMA fully serial; both
// LDS (~50%) and MFMA (~32%) pipes half-idle).
//
// Ledger (3 staging loads/thread/tile, FIFO):
//   head of iter t: staged through t+2 -> outstanding <= 6 (t+1,t+2).
//   rem>=2 -> vmcnt(3) proves t+1 landed (needed: we READ t+1 this iter).
//   rem<2  -> vmcnt(0).
//   stage(t+3) -> slot (t-1)&3: its reads were issued in iter t-2 and
//   lgkm-drained before iter t-1's MFMA, which precedes this iter's barrier
//   on every wave -> WAR safe.
// Static dual register sets via 2x-unrolled loop (rule #20: no runtime
// indexing of frag arrays). VGPR_Count is the tell: ~150-190 means the
// pipeline exists; ~88 means the allocator re-serialized (R3 failure mode).
// ---------------------------------------------------------------------------
template <int EPI, bool FUSE3>
__global__ __launch_bounds__(512, 2) void gemm128s(
    const unsigned short* __restrict__ A,
    const unsigned short* __restrict__ Bt0,
    const unsigned short* __restrict__ Bt1,
    const unsigned short* __restrict__ Bt2,
    const float* __restrict__ bias,
    const float* __restrict__ resid,
    void* __restrict__ out0, void* out1, void* out2,
    int Mdim, int Ndim, int K) {
    constexpr int DIST = 3;
    __shared__ unsigned short ldsA[4][128 * 32];   // 8 KB/slot
    __shared__ unsigned short ldsB[4][256 * 32];   // 16 KB/slot -> 96 KiB
    int tid = threadIdx.x;
    int lane = tid & 63, wave = tid >> 6;
    int l15 = lane & 15, quad = lane >> 4;
    int wr = wave >> 2;        // 0..1 -> rows wr*64..
    int wc = wave & 3;         // 0..3 -> cols wc*64..
    int rt = blockIdx.y * 128;
    const unsigned short* Bt = Bt0;
    void* outp = out0;
    int ct;
    if (FUSE3) {
        int sel = blockIdx.x >> 2;
        ct = (blockIdx.x & 3) * 256;
        Bt   = sel == 0 ? Bt0  : (sel == 1 ? Bt1  : Bt2);
        outp = sel == 0 ? out0 : (sel == 1 ? out1 : out2);
    } else {
        ct = blockIdx.x * 256;
    }

    // staging sources (inverse swizzle on global addr; LDS dest stays linear)
    const unsigned short* aSrc;
    {
        int p = tid >> 3, sp = (tid & 7) ^ (p & 7);
        int rrow = 2 * p + (sp >> 2), g2 = sp & 3;
        int ar = rt + rrow; if (ar >= Mdim) ar = Mdim - 1;
        aSrc = A + (size_t)ar * K + g2 * 8;
    }
    const unsigned short* bSrc[2];
#pragma unroll
    for (int j = 0; j < 2; ++j) {
        int gl = tid + j * 512;
        int p = gl >> 3, sp = (gl & 7) ^ (p & 7);
        int rrow = 2 * p + (sp >> 2), g2 = sp & 3;
        bSrc[j] = Bt + (size_t)(ct + rrow) * K + g2 * 8;
    }
    auto stage = [&](int kt) {
        int sl = kt & 3;
        gload_lds16(aSrc + (size_t)kt * 32, (char*)ldsA[sl] + wave * 1024);
        gload_lds16(bSrc[0] + (size_t)kt * 32, (char*)ldsB[sl] + wave * 1024);
        gload_lds16(bSrc[1] + (size_t)kt * 32, (char*)ldsB[sl] + 8192 + wave * 1024);
    };

    // fragment read offsets (lane-constant swizzle slot; proven 0-conflict)
    int lh = l15 >> 1;
    int mslot = (quad + ((l15 & 1) << 2)) ^ lh;
    unsigned aOff = (unsigned)((wr * 32 + lh) * 128 + mslot * 16);
    unsigned bOff = (unsigned)((wc * 32 + lh) * 128 + mslot * 16);

    f32x4_t acc[4][4] = {};
    int NT = K >> 5;   // BK=32; NT even (32 or 128) at all call sites

    stage(0); stage(1); stage(2);
    asm volatile("s_waitcnt vmcnt(6)" ::: "memory");   // tile 0 landed
    __builtin_amdgcn_s_barrier();

    short8_t afA[4], bfA[4], afB[4], bfB[4];
    {   // prologue: reads of tile 0 -> set A
        const char* la = (const char*)ldsA[0];
        const char* lb = (const char*)ldsB[0];
#pragma unroll
        for (int mi = 0; mi < 4; ++mi) afA[mi] = *(const short8_t*)(la + aOff + mi * 1024);
#pragma unroll
        for (int ni = 0; ni < 4; ++ni) bfA[ni] = *(const short8_t*)(lb + bOff + ni * 1024);
    }

    auto iter = [&](int t, short8_t (&afc)[4], short8_t (&bfc)[4],
                    short8_t (&afn)[4], short8_t (&bfn)[4]) {
        int rem = NT - 1 - t;
        if (rem >= 2) asm volatile("s_waitcnt vmcnt(3)" ::: "memory");
        else          asm volatile("s_waitcnt vmcnt(0)" ::: "memory");
        __builtin_amdgcn_s_barrier();
        if (t + 1 < NT) {
            const char* la = (const char*)ldsA[(t + 1) & 3];
            const char* lb = (const char*)ldsB[(t + 1) & 3];
#pragma unroll
            for (int mi = 0; mi < 4; ++mi) afn[mi] = *(const short8_t*)(la + aOff + mi * 1024);
#pragma unroll
            for (int ni = 0; ni < 4; ++ni) bfn[ni] = *(const short8_t*)(lb + bOff + ni * 1024);
        }
        if (t + DIST < NT) stage(t + DIST);
        if (t + 1 < NT) asm volatile("s_waitcnt lgkmcnt(8)" ::: "memory");
        else            asm volatile("s_waitcnt lgkmcnt(0)" ::: "memory");
        __builtin_amdgcn_sched_barrier(0);
        __builtin_amdgcn_s_setprio(1);
#pragma unroll
        for (int mi = 0; mi < 4; ++mi)
#pragma unroll
            for (int ni = 0; ni < 4; ++ni)
                acc[mi][ni] = mfma_bf16(afc[mi], bfc[ni], acc[mi][ni]);
        __builtin_amdgcn_s_setprio(0);
    };

    for (int t = 0; t < NT; t += 2) {
        iter(t,     afA, bfA, afB, bfB);   // consume A, prefetch into B
        iter(t + 1, afB, bfB, afA, bfA);   // consume B, prefetch into A
    }

    float bias_c[4];
    if (EPI != EPI_BF16) {
#pragma unroll
        for (int ni = 0; ni < 4; ++ni) bias_c[ni] = bias[ct + wc * 64 + ni * 16 + l15];
    }

    // epilogue: C/D layout col=lane&15, row=quad*4+reg
#pragma unroll
    for (int mi = 0; mi < 4; ++mi) {
#pragma unroll
        for (int r = 0; r < 4; ++r) {
            int grow = rt + wr * 64 + mi * 16 + quad * 4 + r;
            if (grow >= Mdim) continue;
#pragma unroll
            for (int ni = 0; ni < 4; ++ni) {
                int gcol = ct + wc * 64 + ni * 16 + l15;
                float v = acc[mi][ni][r];
                size_t idx = (size_t)grow * Ndim + gcol;
                if (EPI == EPI_BF16) {
                    ((unsigned short*)outp)[idx] = f2bf(v);
                } else if (EPI == EPI_GELU) {
                    v += bias_c[ni];
                    ((unsigned short*)outp)[idx] = f2bf(gelu_fast(v));
                } else {
                    v += bias_c[ni] + resid[idx];
                    ((float*)outp)[idx] = v;
                }
            }
        }
    }
}

// ---------------------------------------------------------------------------
// Flash attention v3: triangle-balanced + double-buffered DMA staging.
// (unchanged — proven)
// ---------------------------------------------------------------------------
__global__ __launch_bounds__(256) void attn_kernel(
    const unsigned short* __restrict__ q,
    const unsigned short* __restrict__ k,
    const unsigned short* __restrict__ vt,
    unsigned short* __restrict__ att) {
    int p = blockIdx.x, h = blockIdx.y, b = blockIdx.z;
    int tid = threadIdx.x, lane = tid & 63, wave = tid >> 6;
    int l15 = lane & 15, quad = lane >> 4;
    __shared__ unsigned short kt_lds[2][64 * 64];
    __shared__ unsigned short vt_lds[2][64 * 64];
    __shared__ unsigned short p_lds[4][32 * 64];
    unsigned short* pw = p_lds[wave];

    const int qtA = p, qtB = 7 - p;
    const int tA = 2 * qtA + 2, tB = 2 * qtB + 2, total = tA + tB;  // == 18

    short8_t aq[2][2][2];  // [phase][g][kc]
#pragma unroll
    for (int ph = 0; ph < 2; ++ph) {
        int qw = (ph ? qtB : qtA) * 128 + wave * 32;
#pragma unroll
        for (int g = 0; g < 2; ++g) {
            int qr = qw + g * 16 + l15; if (qr > SEQ - 1) qr = SEQ - 1;
            const unsigned short* qp = q + ((size_t)(b * SEQ + qr)) * D_MODEL + h * 64 + quad * 8;
            aq[ph][g][0] = *(const short8_t*)qp;
            aq[ph][g][1] = *(const short8_t*)(qp + 32);
        }
    }

    f32x4_t o[2][4] = {};
    float m_run[2] = {-3.0e38f, -3.0e38f};
    float l_run[2] = {0.f, 0.f};

    auto stage = [&](int kt, int bufi) {
#pragma unroll
        for (int i = 0; i < 2; ++i) {
            int g2 = tid + i * 256;
            int row = g2 >> 3, cp = g2 & 7;
            int c = cp ^ (row & 7);
            int key = kt * 64 + row; int keyc = key < SEQ ? key : SEQ - 1;
            gload_lds16(k + ((size_t)(b * SEQ + keyc)) * D_MODEL + h * 64 + c * 8,
                        (char*)kt_lds[bufi] + (size_t)(wave * 64 + i * 256) * 16);
            gload_lds16(vt + ((size_t)((b * N_HEADS + h) * 64 + row)) * 1024 + kt * 64 + c * 8,
                        (char*)vt_lds[bufi] + (size_t)(wave * 64 + i * 256) * 16);
        }
    };

    auto flush = [&](int qt) {
#pragma unroll
        for (int g = 0; g < 2; ++g) {
            float linv = __builtin_amdgcn_rcpf(l_run[g]);
#pragma unroll
            for (int r = 0; r < 4; ++r) {
                float nr = __shfl(linv, quad * 4 + r, 64);
                int qg = qt * 128 + wave * 32 + g * 16 + quad * 4 + r;
                if (qg >= SEQ) continue;
#pragma unroll
                for (int db = 0; db < 4; ++db)
                    att[((size_t)(b * SEQ + qg)) * D_MODEL + h * 64 + db * 16 + l15] =
                        f2bf(o[g][db][r] * nr);
            }
        }
#pragma unroll
        for (int g = 0; g < 2; ++g) {
            m_run[g] = -3.0e38f; l_run[g] = 0.f;
#pragma unroll
            for (int db = 0; db < 4; ++db) o[g][db] = f32x4_t{0.f, 0.f, 0.f, 0.f};
        }
    };

    stage(0, 0);

    for (int i = 0; i < total; ++i) {
        int bufi = i & 1;
        __syncthreads();
        if (i + 1 < total) {
            int nkt = (i + 1 < tA) ? (i + 1) : (i + 1 - tA);
            stage(nkt, bufi ^ 1);
        }
        int phase = (i < tA) ? 0 : 1;
        int kt = (i < tA) ? i : i - tA;
        int qt = phase ? qtB : qtA;
        int qw = qt * 128 + wave * 32;
        const unsigned short* kl = kt_lds[bufi];
        const unsigned short* vl = vt_lds[bufi];

        if (kt * 64 <= qw + 31) {
            short8_t kf[4][2];
#pragma unroll
            for (int nb = 0; nb < 4; ++nb)
#pragma unroll
                for (int kc = 0; kc < 2; ++kc) {
                    int row = nb * 16 + l15;
                    kf[nb][kc] = *(const short8_t*)(kl + (row * 8 + ((kc * 4 + quad) ^ (row & 7))) * 8);
                }

            bool gact[2];
#pragma unroll
            for (int g = 0; g < 2; ++g) {
                gact[g] = (kt * 64 <= qw + g * 16 + 15);
                if (!gact[g]) continue;
                f32x4_t s[4] = {};
#pragma unroll
                for (int nb = 0; nb < 4; ++nb)
#pragma unroll
                    for (int kc = 0; kc < 2; ++kc)
                        s[nb] = mfma_bf16(kf[nb][kc], aq[phase][g][kc], s[nb]);
                int qrow = qw + g * 16 + l15;
                float sc[4][4];
#pragma unroll
                for (int nb = 0; nb < 4; ++nb)
#pragma unroll
                    for (int r = 0; r < 4; ++r) {
                        int key = kt * 64 + nb * 16 + quad * 4 + r;
                        float v = s[nb][r] * 0.125f;
                        sc[nb][r] = (key <= qrow) ? v : -1e30f;
                    }
                float mx = sc[0][0];
#pragma unroll
                for (int nb = 0; nb < 4; ++nb)
#pragma unroll
                    for (int r = 0; r < 4; ++r) mx = fmaxf(mx, sc[nb][r]);
                mx = fmaxf(mx, __shfl_xor(mx, 16, 64));
                mx = fmaxf(mx, __shfl_xor(mx, 32, 64));
                float mnew = fmaxf(m_run[g], mx);
                float alpha = __expf(m_run[g] - mnew);
                m_run[g] = mnew;
                float rs = 0.f;
#pragma unroll
                for (int nb = 0; nb < 4; ++nb)
#pragma unroll
                    for (int r = 0; r < 4; ++r) {
                        float pv = __expf(sc[nb][r] - mnew);
                        sc[nb][r] = pv;
                        rs += pv;
                    }
                rs += __shfl_xor(rs, 16, 64);
                rs += __shfl_xor(rs, 32, 64);
                l_run[g] = l_run[g] * alpha + rs;
#pragma unroll
                for (int r = 0; r < 4; ++r) {
                    float a = __shfl(alpha, quad * 4 + r, 64);
#pragma unroll
                    for (int db = 0; db < 4; ++db) o[g][db][r] *= a;
                }
#pragma unroll
                for (int nb = 0; nb < 4; ++nb) {
                    unsigned long long pv =
                        (unsigned long long)f2bf(sc[nb][0]) |
                        ((unsigned long long)f2bf(sc[nb][1]) << 16) |
                        ((unsigned long long)f2bf(sc[nb][2]) << 32) |
                        ((unsigned long long)f2bf(sc[nb][3]) << 48);
                    int chunk = (4 * nb + quad) ^ ((l15 & 7) << 1);
                    *(unsigned long long*)(pw + (g * 16 + l15) * 64 + chunk * 4) = pv;
                }
            }
            asm volatile("s_waitcnt lgkmcnt(0)" ::: "memory");

            short8_t vf[4][2];
#pragma unroll
            for (int db = 0; db < 4; ++db)
#pragma unroll
                for (int kc = 0; kc < 2; ++kc) {
                    int row = db * 16 + l15;
                    vf[db][kc] = *(const short8_t*)(vl + (row * 8 + ((kc * 4 + quad) ^ (row & 7))) * 8);
                }
#pragma unroll
            for (int g = 0; g < 2; ++g) {
                if (!gact[g]) continue;
                short8_t ap[2];
#pragma unroll
                for (int kc = 0; kc < 2; ++kc)
                    ap[kc] = *(const short8_t*)(pw + (g * 16 + l15) * 64 +
                                                ((kc * 4 + quad) ^ (l15 & 7)) * 8);
#pragma unroll
                for (int db = 0; db < 4; ++db)
#pragma unroll
                    for (int kc = 0; kc < 2; ++kc)
                        o[g][db] = mfma_bf16(ap[kc], vf[db][kc], o[g][db]);
            }
        }

        if (i == tA - 1) flush(qtA);
    }
    flush(qtB);
}

// ---------------------------------------------------------------------------
extern "C" void kernel_launch(void* const* d_in, const int* in_sizes, int n_in,
                              void* d_out, int out_size, void* d_ws, size_t ws_size,
                              hipStream_t stream) {
    const float* x     = (const float*)d_in[0];
    const float* wq    = (const float*)d_in[1];
    const float* wk    = (const float*)d_in[2];
    const float* wv    = (const float*)d_in[3];
    const float* wo    = (const float*)d_in[4];
    const float* bo    = (const float*)d_in[5];
    const float* w1    = (const float*)d_in[6];
    const float* b1    = (const float*)d_in[7];
    const float* w2    = (const float*)d_in[8];
    const float* b2    = (const float*)d_in[9];
    const float* g1    = (const float*)d_in[10];
    const float* beta1 = (const float*)d_in[11];
    const float* g2    = (const float*)d_in[12];
    const float* beta2 = (const float*)d_in[13];
    float* out = (float*)d_out;
    char* ws = (char*)d_ws;

    const size_t SZ_MD_BF16 = (size_t)M_TOK * D_MODEL * 2;  // 16,384,000
    unsigned short* h1  = (unsigned short*)(ws);                       // also h2 (alias)
    unsigned short* qb  = (unsigned short*)(ws + SZ_MD_BF16);
    unsigned short* kb  = (unsigned short*)(ws + 2 * SZ_MD_BF16);
    unsigned short* vb  = (unsigned short*)(ws + 3 * SZ_MD_BF16);
    unsigned short* atb = (unsigned short*)(ws + 4 * SZ_MD_BF16);
    unsigned short* ffb = qb;                                          // alias: q..att dead after WO
    size_t off = 5 * SZ_MD_BF16;
    unsigned short* vtb = (unsigned short*)(ws + off); off += (size_t)BATCH * D_MODEL * 1024 * 2; // 16.78MB
    float* x1 = (float*)(ws + off); off += (size_t)M_TOK * D_MODEL * 4;
    unsigned short* wqt = (unsigned short*)(ws + off); off += (size_t)D_MODEL * D_MODEL * 2;
    unsigned short* wkt = (unsigned short*)(ws + off); off += (size_t)D_MODEL * D_MODEL * 2;
    unsigned short* wvt = (unsigned short*)(ws + off); off += (size_t)D_MODEL * D_MODEL * 2;
    unsigned short* wot = (unsigned short*)(ws + off); off += (size_t)D_MODEL * D_MODEL * 2;
    unsigned short* w1t = (unsigned short*)(ws + off); off += (size_t)D_MODEL * D_FF * 2;
    unsigned short* w2t = (unsigned short*)(ws + off); off += (size_t)D_MODEL * D_FF * 2;

    // all weight transposes + LN1 in one launch
    prep_kernel<<<12288 + M_TOK, 256, 0, stream>>>(
        wq, wk, wv, wo, w1, w2, wqt, wkt, wvt, wot, w1t, w2t, x, g1, beta1, h1);

    const int MT128 = (M_TOK + 127) / 128;  // 63

    // QKV fused: 12 x 63 = 756 blocks
    gemm128s<EPI_BF16, true><<<dim3(12, MT128), 512, 0, stream>>>(
        h1, wqt, wkt, wvt, nullptr, nullptr, qb, kb, vb, M_TOK, D_MODEL, D_MODEL);

    dim3 tb(32, 8);
    vtrans_kernel<<<dim3(32, 32, 8), tb, 0, stream>>>(vb, vtb);

    attn_kernel<<<dim3(4, N_HEADS, BATCH), 256, 0, stream>>>(qb, kb, vtb, atb);

    // WO: 4 x 63 = 252 blocks
    gemm128s<EPI_RES_F32, false><<<dim3(4, MT128), 512, 0, stream>>>(
        atb, wot, nullptr, nullptr, bo, x, x1, nullptr, nullptr, M_TOK, D_MODEL, D_MODEL);

    ln_kernel<<<M_TOK, 256, 0, stream>>>(x1, g2, beta2, h1);  // h2 aliases h1

    // FFN1: 16 x 63 = 1008 blocks
    gemm128s<EPI_GELU, false><<<dim3(16, MT128), 512, 0, stream>>>(
        h1, w1t, nullptr, nullptr, b1, nullptr, ffb, nullptr, nullptr, M_TOK, D_FF, D_MODEL);

    // FFN2: 4 x 63 = 252 blocks, K=4096
    gemm128s<EPI_RES_F32, false><<<dim3(4, MT128), 512, 0, stream>>>(
        ffb, w2t, nullptr, nullptr, b2, x1, out, nullptr, nullptr, M_TOK, D_MODEL, D_FF);
}

// Round 6
// 472.555 us; speedup vs baseline: 1.0482x; 1.0482x over previous
//
#include <hip/hip_runtime.h>
#include <hip/hip_bf16.h>
#include <math.h>

#define D_MODEL 1024
#define D_FF    4096
#define N_HEADS 16
#define SEQ     1000
#define BATCH   8
#define M_TOK   (BATCH * SEQ)   // 8000 tokens

typedef __bf16 bf16x8_t __attribute__((ext_vector_type(8)));
typedef short  short8_t __attribute__((ext_vector_type(8)));
typedef float  f32x4_t  __attribute__((ext_vector_type(4)));

__device__ __forceinline__ f32x4_t mfma_bf16(short8_t a, short8_t b, f32x4_t c) {
    return __builtin_amdgcn_mfma_f32_16x16x32_bf16(
        __builtin_bit_cast(bf16x8_t, a), __builtin_bit_cast(bf16x8_t, b), c, 0, 0, 0);
}

// fp32 -> bf16 round-to-nearest-even
__device__ __forceinline__ unsigned short f2bf(float f) {
    union { float f; unsigned u; } x; x.f = f;
    unsigned r = (x.u + 0x7fffu + ((x.u >> 16) & 1u)) >> 16;
    return (unsigned short)r;
}

// fast GELU (tanh form): max abs dev vs exact erf-GELU ~3e-4, below bf16 rounding
__device__ __forceinline__ float gelu_fast(float v) {
    float z = 1.5957691216f * v * fmaf(0.044715f, v * v, 1.0f);
    float e = __expf(-z);                       // v_exp_f32
    return v * __builtin_amdgcn_rcpf(1.0f + e); // v_rcp_f32
}

// async global(16B/lane) -> LDS (wave-uniform base + lane*16)
__device__ __forceinline__ void gload_lds16(const void* g, void* l) {
    __builtin_amdgcn_global_load_lds(
        (const __attribute__((address_space(1))) unsigned int*)g,
        (__attribute__((address_space(3))) unsigned int*)l, 16, 0, 0);
}

// ---------------------------------------------------------------------------
// Prep: all 6 weight transposes (fp32 [K][N] -> bf16 [N][K]) + LN1, one launch.
// ---------------------------------------------------------------------------
__global__ __launch_bounds__(256) void prep_kernel(
    const float* __restrict__ wq, const float* __restrict__ wk,
    const float* __restrict__ wv, const float* __restrict__ wo,
    const float* __restrict__ w1, const float* __restrict__ w2,
    unsigned short* __restrict__ wqt, unsigned short* __restrict__ wkt,
    unsigned short* __restrict__ wvt, unsigned short* __restrict__ wot,
    unsigned short* __restrict__ w1t, unsigned short* __restrict__ w2t,
    const float* __restrict__ x, const float* __restrict__ g1,
    const float* __restrict__ beta1, unsigned short* __restrict__ h1) {
    int id = blockIdx.x;
    __shared__ float tile[32][33];
    __shared__ float red[8];
    if (id >= 12288) {
        // ---- LayerNorm row ----
        int row = id - 12288, tid = threadIdx.x;
        const float4 v = ((const float4*)(x + (size_t)row * D_MODEL))[tid];
        float s  = v.x + v.y + v.z + v.w;
        float s2 = v.x * v.x + v.y * v.y + v.z * v.z + v.w * v.w;
#pragma unroll
        for (int o = 32; o > 0; o >>= 1) { s += __shfl_xor(s, o, 64); s2 += __shfl_xor(s2, o, 64); }
        int wave = tid >> 6, lane = tid & 63;
        if (lane == 0) { red[wave] = s; red[wave + 4] = s2; }
        __syncthreads();
        s  = red[0] + red[1] + red[2] + red[3];
        s2 = red[4] + red[5] + red[6] + red[7];
        float mean = s * (1.0f / D_MODEL);
        float var  = s2 * (1.0f / D_MODEL) - mean * mean;
        float rstd = rsqrtf(var + 1e-5f);
        float4 gg = ((const float4*)g1)[tid];
        float4 bb = ((const float4*)beta1)[tid];
        ushort4 o4;
        o4.x = f2bf((v.x - mean) * rstd * gg.x + bb.x);
        o4.y = f2bf((v.y - mean) * rstd * gg.y + bb.y);
        o4.z = f2bf((v.z - mean) * rstd * gg.z + bb.z);
        o4.w = f2bf((v.w - mean) * rstd * gg.w + bb.w);
        ((ushort4*)(h1 + (size_t)row * D_MODEL))[tid] = o4;
        return;
    }
    // ---- weight transpose ----
    const float* w; unsigned short* wt; int Kd, Nd, bx, by;
    if (id < 4096) {
        int z = id >> 10, t = id & 1023;
        w  = z == 0 ? wq  : z == 1 ? wk  : z == 2 ? wv  : wo;
        wt = z == 0 ? wqt : z == 1 ? wkt : z == 2 ? wvt : wot;
        Kd = 1024; Nd = 1024; bx = t & 31; by = t >> 5;
    } else if (id < 8192) {
        int t = id - 4096;
        w = w1; wt = w1t; Kd = 1024; Nd = 4096; bx = t & 127; by = t >> 7;
    } else {
        int t = id - 8192;
        w = w2; wt = w2t; Kd = 4096; Nd = 1024; bx = t & 31; by = t >> 5;
    }
    int n0 = bx * 32, k0 = by * 32;
    int tx = threadIdx.x & 31, ty = threadIdx.x >> 5;  // 32 x 8
#pragma unroll
    for (int i = 0; i < 4; ++i)
        tile[ty + i * 8][tx] = w[(size_t)(k0 + ty + i * 8) * Nd + n0 + tx];
    __syncthreads();
#pragma unroll
    for (int i = 0; i < 4; ++i)
        wt[(size_t)(n0 + ty + i * 8) * Kd + k0 + tx] = f2bf(tile[tx][ty + i * 8]);
}

// ---------------------------------------------------------------------------
// V transpose: v bf16 [b*1000+s][h*64+dk] -> vt bf16 [b][h*64+dk][1024] (s pad 0)
// ---------------------------------------------------------------------------
__global__ __launch_bounds__(256) void vtrans_kernel(const unsigned short* __restrict__ v,
                                                     unsigned short* __restrict__ vt) {
    __shared__ unsigned short tile[32][33];
    int b = blockIdx.z;
    int c0 = blockIdx.x * 32, s0 = blockIdx.y * 32;
    int tx = threadIdx.x, ty = threadIdx.y;
#pragma unroll
    for (int i = 0; i < 4; ++i) {
        int s = s0 + ty + i * 8;
        unsigned short val = 0;
        if (s < SEQ) val = v[((size_t)b * SEQ + s) * D_MODEL + c0 + tx];
        tile[ty + i * 8][tx] = val;
    }
    __syncthreads();
#pragma unroll
    for (int i = 0; i < 4; ++i) {
        int c = c0 + ty + i * 8;
        vt[((size_t)b * D_MODEL + c) * 1024 + s0 + tx] = tile[tx][ty + i * 8];
    }
}

// ---------------------------------------------------------------------------
// LayerNorm: x fp32 [row][1024] -> out bf16, 1 block per row
// ---------------------------------------------------------------------------
__global__ __launch_bounds__(256) void ln_kernel(const float* __restrict__ x,
                                                 const float* __restrict__ g,
                                                 const float* __restrict__ beta,
                                                 unsigned short* __restrict__ out) {
    int row = blockIdx.x, tid = threadIdx.x;
    const float4 v = ((const float4*)(x + (size_t)row * D_MODEL))[tid];
    float s  = v.x + v.y + v.z + v.w;
    float s2 = v.x * v.x + v.y * v.y + v.z * v.z + v.w * v.w;
#pragma unroll
    for (int o = 32; o > 0; o >>= 1) { s += __shfl_xor(s, o, 64); s2 += __shfl_xor(s2, o, 64); }
    __shared__ float red[8];
    int wave = tid >> 6, lane = tid & 63;
    if (lane == 0) { red[wave] = s; red[wave + 4] = s2; }
    __syncthreads();
    s  = red[0] + red[1] + red[2] + red[3];
    s2 = red[4] + red[5] + red[6] + red[7];
    float mean = s * (1.0f / D_MODEL);
    float var  = s2 * (1.0f / D_MODEL) - mean * mean;
    float rstd = rsqrtf(var + 1e-5f);
    float4 gg = ((const float4*)g)[tid];
    float4 bb = ((const float4*)beta)[tid];
    ushort4 o4;
    o4.x = f2bf((v.x - mean) * rstd * gg.x + bb.x);
    o4.y = f2bf((v.y - mean) * rstd * gg.y + bb.y);
    o4.z = f2bf((v.z - mean) * rstd * gg.z + bb.z);
    o4.w = f2bf((v.w - mean) * rstd * gg.w + bb.w);
    ((ushort4*)(out + (size_t)row * D_MODEL))[tid] = o4;
}

enum { EPI_BF16 = 0, EPI_GELU = 1, EPI_RES_F32 = 2 };

// ---------------------------------------------------------------------------
// gemm128t SLOTS=4: R2-proven 128x256 / BK=32 / 4-slot ring / counted vmcnt.
// Kept byte-identical for WO + FFN2 (252-block grids).
// ---------------------------------------------------------------------------
template <int EPI, bool FUSE3, int SLOTS>
__global__ __launch_bounds__(512, 2) void gemm128t(
    const unsigned short* __restrict__ A,
    const unsigned short* __restrict__ Bt0,
    const unsigned short* __restrict__ Bt1,
    const unsigned short* __restrict__ Bt2,
    const float* __restrict__ bias,
    const float* __restrict__ resid,
    void* __restrict__ out0, void* out1, void* out2,
    int Mdim, int Ndim, int K) {
    constexpr int DIST = SLOTS - 1;
    __shared__ unsigned short ldsA[SLOTS][128 * 32];   // 8 KB/slot
    __shared__ unsigned short ldsB[SLOTS][256 * 32];   // 16 KB/slot
    int tid = threadIdx.x;
    int lane = tid & 63, wave = tid >> 6;
    int l15 = lane & 15, quad = lane >> 4;
    int wr = wave >> 2;
    int wc = wave & 3;
    int rt = blockIdx.y * 128;
    const unsigned short* Bt = Bt0;
    void* outp = out0;
    int ct;
    if (FUSE3) {
        int sel = blockIdx.x >> 2;
        ct = (blockIdx.x & 3) * 256;
        Bt   = sel == 0 ? Bt0  : (sel == 1 ? Bt1  : Bt2);
        outp = sel == 0 ? out0 : (sel == 1 ? out1 : out2);
    } else {
        ct = blockIdx.x * 256;
    }

    const unsigned short* aSrc;
    {
        int p = tid >> 3, sp = (tid & 7) ^ (p & 7);
        int rrow = 2 * p + (sp >> 2), g2 = sp & 3;
        int ar = rt + rrow; if (ar >= Mdim) ar = Mdim - 1;
        aSrc = A + (size_t)ar * K + g2 * 8;
    }
    const unsigned short* bSrc[2];
#pragma unroll
    for (int j = 0; j < 2; ++j) {
        int gl = tid + j * 512;
        int p = gl >> 3, sp = (gl & 7) ^ (p & 7);
        int rrow = 2 * p + (sp >> 2), g2 = sp & 3;
        bSrc[j] = Bt + (size_t)(ct + rrow) * K + g2 * 8;
    }
    auto stage = [&](int kt, int sl) {
        gload_lds16(aSrc + (size_t)kt * 32, (char*)ldsA[sl] + wave * 1024);
        gload_lds16(bSrc[0] + (size_t)kt * 32, (char*)ldsB[sl] + wave * 1024);
        gload_lds16(bSrc[1] + (size_t)kt * 32, (char*)ldsB[sl] + 8192 + wave * 1024);
    };

    int lh = l15 >> 1;
    int mslot = (quad + ((l15 & 1) << 2)) ^ lh;
    unsigned aOff = (unsigned)((wr * 32 + lh) * 128 + mslot * 16);
    unsigned bOff = (unsigned)((wc * 32 + lh) * 128 + mslot * 16);

    f32x4_t acc[4][4] = {};
    int NT = K >> 5;

#pragma unroll
    for (int d = 0; d < DIST; ++d) stage(d, d);

    int scur = 0, spre = DIST;
    for (int t = 0; t < NT; ++t) {
        int rem = NT - 1 - t;
        if constexpr (SLOTS == 4) {
            if (rem >= 2)      asm volatile("s_waitcnt vmcnt(6)" ::: "memory");
            else if (rem == 1) asm volatile("s_waitcnt vmcnt(3)" ::: "memory");
            else               asm volatile("s_waitcnt vmcnt(0)" ::: "memory");
        } else {
            if (rem >= 1)      asm volatile("s_waitcnt vmcnt(3)" ::: "memory");
            else               asm volatile("s_waitcnt vmcnt(0)" ::: "memory");
        }
        __builtin_amdgcn_s_barrier();
        const char* la = (const char*)ldsA[scur];
        const char* lb = (const char*)ldsB[scur];
        short8_t af[4], bfv[4];
#pragma unroll
        for (int mi = 0; mi < 4; ++mi)
            af[mi] = *(const short8_t*)(la + aOff + mi * 1024);
#pragma unroll
        for (int ni = 0; ni < 4; ++ni)
            bfv[ni] = *(const short8_t*)(lb + bOff + ni * 1024);
        if (t + DIST < NT) stage(t + DIST, spre);
        __builtin_amdgcn_s_setprio(1);
#pragma unroll
        for (int mi = 0; mi < 4; ++mi)
#pragma unroll
            for (int ni = 0; ni < 4; ++ni)
                acc[mi][ni] = mfma_bf16(af[mi], bfv[ni], acc[mi][ni]);
        __builtin_amdgcn_s_setprio(0);
        scur = (scur == SLOTS - 1) ? 0 : scur + 1;
        spre = (spre == SLOTS - 1) ? 0 : spre + 1;
    }

    float bias_c[4];
    if (EPI != EPI_BF16) {
#pragma unroll
        for (int ni = 0; ni < 4; ++ni) bias_c[ni] = bias[ct + wc * 64 + ni * 16 + l15];
    }

#pragma unroll
    for (int mi = 0; mi < 4; ++mi) {
#pragma unroll
        for (int r = 0; r < 4; ++r) {
            int grow = rt + wr * 64 + mi * 16 + quad * 4 + r;
            if (grow >= Mdim) continue;
#pragma unroll
            for (int ni = 0; ni < 4; ++ni) {
                int gcol = ct + wc * 64 + ni * 16 + l15;
                float v = acc[mi][ni][r];
                size_t idx = (size_t)grow * Ndim + gcol;
                if (EPI == EPI_BF16) {
                    ((unsigned short*)outp)[idx] = f2bf(v);
                } else if (EPI == EPI_GELU) {
                    v += bias_c[ni];
                    ((unsigned short*)outp)[idx] = f2bf(gelu_fast(v));
                } else {
                    v += bias_c[ni] + resid[idx];
                    ((float*)outp)[idx] = v;
                }
            }
        }
    }
}

// ---------------------------------------------------------------------------
// gemm256ph: faithful port of the m201 8-phase 256^2 template.
// 256x256 tile, BK=64, 8 waves (2M x 4N), per-wave 128x64 (acc[8][4]),
// LDS 128 KiB = 2 slots x {A: [half][128r][8sl][16B] 32KB, B: [qtr][64r][8sl][16B] 32KB}.
//
// Staged units (16 KB, 2 gload/thread): A_lo (rows 0-63 of both halves),
// A_hi, B_lo (rows 0-31 of all quarters), B_hi. Read: p1={A_lo,B_lo},
// p2={B_hi}, p3={A_hi}, p4={} (regs). Stage: p1:(kt+1).B_hi,
// p2:(kt+2).A_lo, p3:(kt+2).B_lo, p4:(kt+2).A_hi.
// Phase = {reads | stage} BAR lgkm0 SB prio1 16xMFMA prio0 BAR.
// vmcnt(6) ONCE per tile at p4 AFTER its stage: newest 3 units are the
// p2/p3/p4 stages -> proves (kt+1) fully landed; the following barrier
// completes the cross-wave proof (each wave vouches for its own loads).
// Never drains to 0 except the last two tiles. WAR: each stage targets a
// region whose last reader phase completed (double-barrier cadence).
// Swizzle: slot8 = (kk*4+quad) ^ (l15&7) on read; inverse on global src.
// ---------------------------------------------------------------------------
template <int EPI, bool FUSE3>
__global__ __launch_bounds__(512, 2) void gemm256ph(
    const unsigned short* __restrict__ A,
    const unsigned short* __restrict__ Bt0,
    const unsigned short* __restrict__ Bt1,
    const unsigned short* __restrict__ Bt2,
    const float* __restrict__ bias,
    const float* __restrict__ resid,
    void* __restrict__ out0, void* out1, void* out2,
    int Mdim, int Ndim, int K) {
    __shared__ unsigned short lds[2][32768];   // 2 slots x 64 KB = 128 KiB
    int tid = threadIdx.x;
    int lane = tid & 63, wave = tid >> 6;
    int l15 = lane & 15, quad = lane >> 4;
    int wr = wave >> 2;         // A half (128 rows each)
    int wc = wave & 3;          // B quarter (64 cols each)
    int rt = blockIdx.y * 256;
    const unsigned short* Bt = Bt0;
    void* outp = out0;
    int ct;
    if (FUSE3) {
        int sel = blockIdx.x >> 2;
        ct = (blockIdx.x & 3) * 256;
        Bt   = sel == 0 ? Bt0  : (sel == 1 ? Bt1  : Bt2);
        outp = sel == 0 ? out0 : (sel == 1 ? out1 : out2);
    } else {
        ct = blockIdx.x * 256;
    }

    // staging sources (inverse swizzle on global col; LDS dest linear)
    int r6 = tid >> 3, s8 = tid & 7;
    int gswA = (s8 ^ (r6 & 7)) * 8;
    const unsigned short* aP[2][2];   // [piece j=half][h=lo/hi]
#pragma unroll
    for (int j = 0; j < 2; ++j)
#pragma unroll
        for (int h = 0; h < 2; ++h) {
            int ar = rt + j * 128 + h * 64 + r6;
            if (ar >= Mdim) ar = Mdim - 1;
            aP[j][h] = A + (size_t)ar * K + gswA;
        }
    const unsigned short* bP[2][2];
#pragma unroll
    for (int j = 0; j < 2; ++j) {
        int G = tid + j * 512;
        int q = G >> 8, idx = G & 255;
        int r5 = idx >> 3, sb = idx & 7;
        int gswB = (sb ^ (r5 & 7)) * 8;
#pragma unroll
        for (int h = 0; h < 2; ++h)
            bP[j][h] = Bt + (size_t)(ct + q * 64 + h * 32 + r5) * K + gswB;
    }
    char* ldsb = (char*)lds;
    int bwoff = (wave >> 2) * 8192 + (wave & 3) * 1024;  // B dest wave offset
    auto stA = [&](int kt, int h) {
        char* d = ldsb + (size_t)(kt & 1) * 65536 + h * 8192 + wave * 1024;
        gload_lds16(aP[0][h] + (size_t)kt * 64, d);
        gload_lds16(aP[1][h] + (size_t)kt * 64, d + 16384);
    };
    auto stB = [&](int kt, int h) {
        char* d = ldsb + (size_t)(kt & 1) * 65536 + 32768 + h * 4096 + bwoff;
        gload_lds16(bP[0][h] + (size_t)kt * 64, d);
        gload_lds16(bP[1][h] + (size_t)kt * 64, d + 16384);
    };

    // read offsets: A(mi,kk) = slot + aB + swk + mi*2048 ; B(ni,kk) = slot + bB + swk + ni*2048
    unsigned sw0 = (unsigned)((quad ^ (l15 & 7)) * 16);
    unsigned sw1 = sw0 ^ 64;
    unsigned aB = (unsigned)(wr * 16384 + l15 * 128);
    unsigned bB = (unsigned)(32768 + wc * 8192 + l15 * 128);

    f32x4_t acc[8][4] = {};
    int NT = K >> 6;   // BK=64; NT>=16 at all call sites

    // prologue: tile0 all 4 units + tile1 {A_lo,B_lo,A_hi}; t1.B_hi comes at t0.p1
    stA(0, 0); stB(0, 0); stA(0, 1); stB(0, 1);
    stA(1, 0); stB(1, 0); stA(1, 1);
    asm volatile("s_waitcnt vmcnt(6)" ::: "memory");   // proves tile 0
    __builtin_amdgcn_s_barrier();

    short8_t af[4][2], bf[4][2];
    for (int kt = 0; kt < NT; ++kt) {
        const char* sbase = ldsb + (size_t)(kt & 1) * 65536;
        // ---- phase 1: read A_lo(8) + B_lo(4) ; stage (kt+1).B_hi ----
#pragma unroll
        for (int mi = 0; mi < 4; ++mi) {
            af[mi][0] = *(const short8_t*)(sbase + aB + sw0 + mi * 2048);
            af[mi][1] = *(const short8_t*)(sbase + aB + sw1 + mi * 2048);
        }
#pragma unroll
        for (int ni = 0; ni < 2; ++ni) {
            bf[ni][0] = *(const short8_t*)(sbase + bB + sw0 + ni * 2048);
            bf[ni][1] = *(const short8_t*)(sbase + bB + sw1 + ni * 2048);
        }
        if (kt + 1 < NT) stB(kt + 1, 1);
        __builtin_amdgcn_s_barrier();
        asm volatile("s_waitcnt lgkmcnt(0)" ::: "memory");
        __builtin_amdgcn_sched_barrier(0);
        __builtin_amdgcn_s_setprio(1);
#pragma unroll
        for (int mi = 0; mi < 4; ++mi)
#pragma unroll
            for (int ni = 0; ni < 2; ++ni) {
                acc[mi][ni] = mfma_bf16(af[mi][0], bf[ni][0], acc[mi][ni]);
                acc[mi][ni] = mfma_bf16(af[mi][1], bf[ni][1], acc[mi][ni]);
            }
        __builtin_amdgcn_s_setprio(0);
        __builtin_amdgcn_s_barrier();
        // ---- phase 2: read B_hi(4) ; stage (kt+2).A_lo ----
#pragma unroll
        for (int ni = 2; ni < 4; ++ni) {
            bf[ni][0] = *(const short8_t*)(sbase + bB + sw0 + ni * 2048);
            bf[ni][1] = *(const short8_t*)(sbase + bB + sw1 + ni * 2048);
        }
        if (kt + 2 < NT) stA(kt + 2, 0);
        __builtin_amdgcn_s_barrier();
        asm volatile("s_waitcnt lgkmcnt(0)" ::: "memory");
        __builtin_amdgcn_sched_barrier(0);
        __builtin_amdgcn_s_setprio(1);
#pragma unroll
        for (int mi = 0; mi < 4; ++mi)
#pragma unroll
            for (int ni = 2; ni < 4; ++ni) {
                acc[mi][ni] = mfma_bf16(af[mi][0], bf[ni][0], acc[mi][ni]);
                acc[mi][ni] = mfma_bf16(af[mi][1], bf[ni][1], acc[mi][ni]);
            }
        __builtin_amdgcn_s_setprio(0);
        __builtin_amdgcn_s_barrier();
        // ---- phase 3: read A_hi(8) (reuse af regs) ; stage (kt+2).B_lo ----
#pragma unroll
        for (int mi = 0; mi < 4; ++mi) {
            af[mi][0] = *(const short8_t*)(sbase + aB + sw0 + (mi + 4) * 2048);
            af[mi][1] = *(const short8_t*)(sbase + aB + sw1 + (mi + 4) * 2048);
        }
        if (kt + 2 < NT) stB(kt + 2, 0);
        __builtin_amdgcn_s_barrier();
        asm volatile("s_waitcnt lgkmcnt(0)" ::: "memory");
        __builtin_amdgcn_sched_barrier(0);
        __builtin_amdgcn_s_setprio(1);
#pragma unroll
        for (int mi = 0; mi < 4; ++mi)
#pragma unroll
            for (int ni = 2; ni < 4; ++ni) {
                acc[mi + 4][ni] = mfma_bf16(af[mi][0], bf[ni][0], acc[mi + 4][ni]);
                acc[mi + 4][ni] = mfma_bf16(af[mi][1], bf[ni][1], acc[mi + 4][ni]);
            }
        __builtin_amdgcn_s_setprio(0);
        __builtin_amdgcn_s_barrier();
        // ---- phase 4: stage (kt+2).A_hi ; vmcnt(6) proving tile kt+1 ----
        if (kt + 2 < NT) {
            stA(kt + 2, 1);
            asm volatile("s_waitcnt vmcnt(6)" ::: "memory");
        } else {
            asm volatile("s_waitcnt vmcnt(0)" ::: "memory");
        }
        __builtin_amdgcn_s_barrier();
        __builtin_amdgcn_sched_barrier(0);
        __builtin_amdgcn_s_setprio(1);
#pragma unroll
        for (int mi = 0; mi < 4; ++mi)
#pragma unroll
            for (int ni = 0; ni < 2; ++ni) {
                acc[mi + 4][ni] = mfma_bf16(af[mi][0], bf[ni][0], acc[mi + 4][ni]);
                acc[mi + 4][ni] = mfma_bf16(af[mi][1], bf[ni][1], acc[mi + 4][ni]);
            }
        __builtin_amdgcn_s_setprio(0);
        __builtin_amdgcn_s_barrier();
    }

    float bias_c[4];
    if (EPI != EPI_BF16) {
#pragma unroll
        for (int ni = 0; ni < 4; ++ni) bias_c[ni] = bias[ct + wc * 64 + ni * 16 + l15];
    }

    // epilogue: C/D layout col=lane&15, row=quad*4+reg
#pragma unroll
    for (int mi = 0; mi < 8; ++mi) {
#pragma unroll
        for (int r = 0; r < 4; ++r) {
            int grow = rt + wr * 128 + mi * 16 + quad * 4 + r;
            if (grow >= Mdim) continue;
#pragma unroll
            for (int ni = 0; ni < 4; ++ni) {
                int gcol = ct + wc * 64 + ni * 16 + l15;
                float v = acc[mi][ni][r];
                size_t idx = (size_t)grow * Ndim + gcol;
                if (EPI == EPI_BF16) {
                    ((unsigned short*)outp)[idx] = f2bf(v);
                } else if (EPI == EPI_GELU) {
                    v += bias_c[ni];
                    ((unsigned short*)outp)[idx] = f2bf(gelu_fast(v));
                } else {
                    v += bias_c[ni] + resid[idx];
                    ((float*)outp)[idx] = v;
                }
            }
        }
    }
}

// ---------------------------------------------------------------------------
// Flash attention v3: triangle-balanced + double-buffered DMA staging.
// (unchanged — proven)
// ---------------------------------------------------------------------------
__global__ __launch_bounds__(256) void attn_kernel(
    const unsigned short* __restrict__ q,
    const unsigned short* __restrict__ k,
    const unsigned short* __restrict__ vt,
    unsigned short* __restrict__ att) {
    int p = blockIdx.x, h = blockIdx.y, b = blockIdx.z;
    int tid = threadIdx.x, lane = tid & 63, wave = tid >> 6;
    int l15 = lane & 15, quad = lane >> 4;
    __shared__ unsigned short kt_lds[2][64 * 64];
    __shared__ unsigned short vt_lds[2][64 * 64];
    __shared__ unsigned short p_lds[4][32 * 64];
    unsigned short* pw = p_lds[wave];

    const int qtA = p, qtB = 7 - p;
    const int tA = 2 * qtA + 2, tB = 2 * qtB + 2, total = tA + tB;  // == 18

    short8_t aq[2][2][2];  // [phase][g][kc]
#pragma unroll
    for (int ph = 0; ph < 2; ++ph) {
        int qw = (ph ? qtB : qtA) * 128 + wave * 32;
#pragma unroll
        for (int g = 0; g < 2; ++g) {
            int qr = qw + g * 16 + l15; if (qr > SEQ - 1) qr = SEQ - 1;
            const unsigned short* qp = q + ((size_t)(b * SEQ + qr)) * D_MODEL + h * 64 + quad * 8;
            aq[ph][g][0] = *(const short8_t*)qp;
            aq[ph][g][1] = *(const short8_t*)(qp + 32);
        }
    }

    f32x4_t o[2][4] = {};
    float m_run[2] = {-3.0e38f, -3.0e38f};
    float l_run[2] = {0.f, 0.f};

    auto stage = [&](int kt, int bufi) {
#pragma unroll
        for (int i = 0; i < 2; ++i) {
            int g2 = tid + i * 256;
            int row = g2 >> 3, cp = g2 & 7;
            int c = cp ^ (row & 7);
            int key = kt * 64 + row; int keyc = key < SEQ ? key : SEQ - 1;
            gload_lds16(k + ((size_t)(b * SEQ + keyc)) * D_MODEL + h * 64 + c * 8,
                        (char*)kt_lds[bufi] + (size_t)(wave * 64 + i * 256) * 16);
            gload_lds16(vt + ((size_t)((b * N_HEADS + h) * 64 + row)) * 1024 + kt * 64 + c * 8,
                        (char*)vt_lds[bufi] + (size_t)(wave * 64 + i * 256) * 16);
        }
    };

    auto flush = [&](int qt) {
#pragma unroll
        for (int g = 0; g < 2; ++g) {
            float linv = __builtin_amdgcn_rcpf(l_run[g]);
#pragma unroll
            for (int r = 0; r < 4; ++r) {
                float nr = __shfl(linv, quad * 4 + r, 64);
                int qg = qt * 128 + wave * 32 + g * 16 + quad * 4 + r;
                if (qg >= SEQ) continue;
#pragma unroll
                for (int db = 0; db < 4; ++db)
                    att[((size_t)(b * SEQ + qg)) * D_MODEL + h * 64 + db * 16 + l15] =
                        f2bf(o[g][db][r] * nr);
            }
        }
#pragma unroll
        for (int g = 0; g < 2; ++g) {
            m_run[g] = -3.0e38f; l_run[g] = 0.f;
#pragma unroll
            for (int db = 0; db < 4; ++db) o[g][db] = f32x4_t{0.f, 0.f, 0.f, 0.f};
        }
    };

    stage(0, 0);

    for (int i = 0; i < total; ++i) {
        int bufi = i & 1;
        __syncthreads();
        if (i + 1 < total) {
            int nkt = (i + 1 < tA) ? (i + 1) : (i + 1 - tA);
            stage(nkt, bufi ^ 1);
        }
        int phase = (i < tA) ? 0 : 1;
        int kt = (i < tA) ? i : i - tA;
        int qt = phase ? qtB : qtA;
        int qw = qt * 128 + wave * 32;
        const unsigned short* kl = kt_lds[bufi];
        const unsigned short* vl = vt_lds[bufi];

        if (kt * 64 <= qw + 31) {
            short8_t kf[4][2];
#pragma unroll
            for (int nb = 0; nb < 4; ++nb)
#pragma unroll
                for (int kc = 0; kc < 2; ++kc) {
                    int row = nb * 16 + l15;
                    kf[nb][kc] = *(const short8_t*)(kl + (row * 8 + ((kc * 4 + quad) ^ (row & 7))) * 8);
                }

            bool gact[2];
#pragma unroll
            for (int g = 0; g < 2; ++g) {
                gact[g] = (kt * 64 <= qw + g * 16 + 15);
                if (!gact[g]) continue;
                f32x4_t s[4] = {};
#pragma unroll
                for (int nb = 0; nb < 4; ++nb)
#pragma unroll
                    for (int kc = 0; kc < 2; ++kc)
                        s[nb] = mfma_bf16(kf[nb][kc], aq[phase][g][kc], s[nb]);
                int qrow = qw + g * 16 + l15;
                float sc[4][4];
#pragma unroll
                for (int nb = 0; nb < 4; ++nb)
#pragma unroll
                    for (int r = 0; r < 4; ++r) {
                        int key = kt * 64 + nb * 16 + quad * 4 + r;
                        float v = s[nb][r] * 0.125f;
                        sc[nb][r] = (key <= qrow) ? v : -1e30f;
                    }
                float mx = sc[0][0];
#pragma unroll
                for (int nb = 0; nb < 4; ++nb)
#pragma unroll
                    for (int r = 0; r < 4; ++r) mx = fmaxf(mx, sc[nb][r]);
                mx = fmaxf(mx, __shfl_xor(mx, 16, 64));
                mx = fmaxf(mx, __shfl_xor(mx, 32, 64));
                float mnew = fmaxf(m_run[g], mx);
                float alpha = __expf(m_run[g] - mnew);
                m_run[g] = mnew;
                float rs = 0.f;
#pragma unroll
                for (int nb = 0; nb < 4; ++nb)
#pragma unroll
                    for (int r = 0; r < 4; ++r) {
                        float pv = __expf(sc[nb][r] - mnew);
                        sc[nb][r] = pv;
                        rs += pv;
                    }
                rs += __shfl_xor(rs, 16, 64);
                rs += __shfl_xor(rs, 32, 64);
                l_run[g] = l_run[g] * alpha + rs;
#pragma unroll
                for (int r = 0; r < 4; ++r) {
                    float a = __shfl(alpha, quad * 4 + r, 64);
#pragma unroll
                    for (int db = 0; db < 4; ++db) o[g][db][r] *= a;
                }
#pragma unroll
                for (int nb = 0; nb < 4; ++nb) {
                    unsigned long long pv =
                        (unsigned long long)f2bf(sc[nb][0]) |
                        ((unsigned long long)f2bf(sc[nb][1]) << 16) |
                        ((unsigned long long)f2bf(sc[nb][2]) << 32) |
                        ((unsigned long long)f2bf(sc[nb][3]) << 48);
                    int chunk = (4 * nb + quad) ^ ((l15 & 7) << 1);
                    *(unsigned long long*)(pw + (g * 16 + l15) * 64 + chunk * 4) = pv;
                }
            }
            asm volatile("s_waitcnt lgkmcnt(0)" ::: "memory");

            short8_t vf[4][2];
#pragma unroll
            for (int db = 0; db < 4; ++db)
#pragma unroll
                for (int kc = 0; kc < 2; ++kc) {
                    int row = db * 16 + l15;
                    vf[db][kc] = *(const short8_t*)(vl + (row * 8 + ((kc * 4 + quad) ^ (row & 7))) * 8);
                }
#pragma unroll
            for (int g = 0; g < 2; ++g) {
                if (!gact[g]) continue;
                short8_t ap[2];
#pragma unroll
                for (int kc = 0; kc < 2; ++kc)
                    ap[kc] = *(const short8_t*)(pw + (g * 16 + l15) * 64 +
                                                ((kc * 4 + quad) ^ (l15 & 7)) * 8);
#pragma unroll
                for (int db = 0; db < 4; ++db)
#pragma unroll
                    for (int kc = 0; kc < 2; ++kc)
                        o[g][db] = mfma_bf16(ap[kc], vf[db][kc], o[g][db]);
            }
        }

        if (i == tA - 1) flush(qtA);
    }
    flush(qtB);
}

// ---------------------------------------------------------------------------
extern "C" void kernel_launch(void* const* d_in, const int* in_sizes, int n_in,
                              void* d_out, int out_size, void* d_ws, size_t ws_size,
                              hipStream_t stream) {
    const float* x     = (const float*)d_in[0];
    const float* wq    = (const float*)d_in[1];
    const float* wk    = (const float*)d_in[2];
    const float* wv    = (const float*)d_in[3];
    const float* wo    = (const float*)d_in[4];
    const float* bo    = (const float*)d_in[5];
    const float* w1    = (const float*)d_in[6];
    const float* b1    = (const float*)d_in[7];
    const float* w2    = (const float*)d_in[8];
    const float* b2    = (const float*)d_in[9];
    const float* g1    = (const float*)d_in[10];
    const float* beta1 = (const float*)d_in[11];
    const float* g2    = (const float*)d_in[12];
    const float* beta2 = (const float*)d_in[13];
    float* out = (float*)d_out;
    char* ws = (char*)d_ws;

    const size_t SZ_MD_BF16 = (size_t)M_TOK * D_MODEL * 2;  // 16,384,000
    unsigned short* h1  = (unsigned short*)(ws);                       // also h2 (alias)
    unsigned short* qb  = (unsigned short*)(ws + SZ_MD_BF16);
    unsigned short* kb  = (unsigned short*)(ws + 2 * SZ_MD_BF16);
    unsigned short* vb  = (unsigned short*)(ws + 3 * SZ_MD_BF16);
    unsigned short* atb = (unsigned short*)(ws + 4 * SZ_MD_BF16);
    unsigned short* ffb = qb;                                          // alias: q..att dead after WO
    size_t off = 5 * SZ_MD_BF16;
    unsigned short* vtb = (unsigned short*)(ws + off); off += (size_t)BATCH * D_MODEL * 1024 * 2; // 16.78MB
    float* x1 = (float*)(ws + off); off += (size_t)M_TOK * D_MODEL * 4;
    unsigned short* wqt = (unsigned short*)(ws + off); off += (size_t)D_MODEL * D_MODEL * 2;
    unsigned short* wkt = (unsigned short*)(ws + off); off += (size_t)D_MODEL * D_MODEL * 2;
    unsigned short* wvt = (unsigned short*)(ws + off); off += (size_t)D_MODEL * D_MODEL * 2;
    unsigned short* wot = (unsigned short*)(ws + off); off += (size_t)D_MODEL * D_MODEL * 2;
    unsigned short* w1t = (unsigned short*)(ws + off); off += (size_t)D_MODEL * D_FF * 2;
    unsigned short* w2t = (unsigned short*)(ws + off); off += (size_t)D_MODEL * D_FF * 2;

    // all weight transposes + LN1 in one launch
    prep_kernel<<<12288 + M_TOK, 256, 0, stream>>>(
        wq, wk, wv, wo, w1, w2, wqt, wkt, wvt, wot, w1t, w2t, x, g1, beta1, h1);

    const int MT128 = (M_TOK + 127) / 128;  // 63
    const int MT256 = (M_TOK + 255) / 256;  // 32

    // QKV fused: 12 x 32 = 384 blocks, 8-phase 256^2
    gemm256ph<EPI_BF16, true><<<dim3(12, MT256), 512, 0, stream>>>(
        h1, wqt, wkt, wvt, nullptr, nullptr, qb, kb, vb, M_TOK, D_MODEL, D_MODEL);

    dim3 tb(32, 8);
    vtrans_kernel<<<dim3(32, 32, 8), tb, 0, stream>>>(vb, vtb);

    attn_kernel<<<dim3(4, N_HEADS, BATCH), 256, 0, stream>>>(qb, kb, vtb, atb);

    // WO: 4 x 63 = 252 blocks, proven SLOTS=4 path
    gemm128t<EPI_RES_F32, false, 4><<<dim3(4, MT128), 512, 0, stream>>>(
        atb, wot, nullptr, nullptr, bo, x, x1, nullptr, nullptr, M_TOK, D_MODEL, D_MODEL);

    ln_kernel<<<M_TOK, 256, 0, stream>>>(x1, g2, beta2, h1);  // h2 aliases h1

    // FFN1: 16 x 32 = 512 blocks = 2 exact occupancy rounds, 8-phase 256^2
    gemm256ph<EPI_GELU, false><<<dim3(16, MT256), 512, 0, stream>>>(
        h1, w1t, nullptr, nullptr, b1, nullptr, ffb, nullptr, nullptr, M_TOK, D_FF, D_MODEL);

    // FFN2: 4 x 63 = 252 blocks, proven SLOTS=4 path (K=4096)
    gemm128t<EPI_RES_F32, false, 4><<<dim3(4, MT128), 512, 0, stream>>>(
        ffb, w2t, nullptr, nullptr, b2, x1, out, nullptr, nullptr, M_TOK, D_MODEL, D_FF);
}

// Round 7
// 464.955 us; speedup vs baseline: 1.0654x; 1.0163x over previous
//
#include <hip/hip_runtime.h>
#include <hip/hip_bf16.h>
#include <math.h>

#define D_MODEL 1024
#define D_FF    4096
#define N_HEADS 16
#define SEQ     1000
#define BATCH   8
#define M_TOK   (BATCH * SEQ)   // 8000 tokens

typedef __bf16 bf16x8_t __attribute__((ext_vector_type(8)));
typedef short  short8_t __attribute__((ext_vector_type(8)));
typedef float  f32x4_t  __attribute__((ext_vector_type(4)));

__device__ __forceinline__ f32x4_t mfma_bf16(short8_t a, short8_t b, f32x4_t c) {
    return __builtin_amdgcn_mfma_f32_16x16x32_bf16(
        __builtin_bit_cast(bf16x8_t, a), __builtin_bit_cast(bf16x8_t, b), c, 0, 0, 0);
}

// fp32 -> bf16 round-to-nearest-even
__device__ __forceinline__ unsigned short f2bf(float f) {
    union { float f; unsigned u; } x; x.f = f;
    unsigned r = (x.u + 0x7fffu + ((x.u >> 16) & 1u)) >> 16;
    return (unsigned short)r;
}

// fast GELU (tanh form): max abs dev vs exact erf-GELU ~3e-4, below bf16 rounding
__device__ __forceinline__ float gelu_fast(float v) {
    float z = 1.5957691216f * v * fmaf(0.044715f, v * v, 1.0f);
    float e = __expf(-z);                       // v_exp_f32
    return v * __builtin_amdgcn_rcpf(1.0f + e); // v_rcp_f32
}

// async global(16B/lane) -> LDS (wave-uniform base + lane*16)
__device__ __forceinline__ void gload_lds16(const void* g, void* l) {
    __builtin_amdgcn_global_load_lds(
        (const __attribute__((address_space(1))) unsigned int*)g,
        (__attribute__((address_space(3))) unsigned int*)l, 16, 0, 0);
}

// ---------------------------------------------------------------------------
// Prep: all 6 weight transposes (fp32 [K][N] -> bf16 [N][K]) + LN1, one launch.
// ---------------------------------------------------------------------------
__global__ __launch_bounds__(256) void prep_kernel(
    const float* __restrict__ wq, const float* __restrict__ wk,
    const float* __restrict__ wv, const float* __restrict__ wo,
    const float* __restrict__ w1, const float* __restrict__ w2,
    unsigned short* __restrict__ wqt, unsigned short* __restrict__ wkt,
    unsigned short* __restrict__ wvt, unsigned short* __restrict__ wot,
    unsigned short* __restrict__ w1t, unsigned short* __restrict__ w2t,
    const float* __restrict__ x, const float* __restrict__ g1,
    const float* __restrict__ beta1, unsigned short* __restrict__ h1) {
    int id = blockIdx.x;
    __shared__ float tile[32][33];
    __shared__ float red[8];
    if (id >= 12288) {
        // ---- LayerNorm row ----
        int row = id - 12288, tid = threadIdx.x;
        const float4 v = ((const float4*)(x + (size_t)row * D_MODEL))[tid];
        float s  = v.x + v.y + v.z + v.w;
        float s2 = v.x * v.x + v.y * v.y + v.z * v.z + v.w * v.w;
#pragma unroll
        for (int o = 32; o > 0; o >>= 1) { s += __shfl_xor(s, o, 64); s2 += __shfl_xor(s2, o, 64); }
        int wave = tid >> 6, lane = tid & 63;
        if (lane == 0) { red[wave] = s; red[wave + 4] = s2; }
        __syncthreads();
        s  = red[0] + red[1] + red[2] + red[3];
        s2 = red[4] + red[5] + red[6] + red[7];
        float mean = s * (1.0f / D_MODEL);
        float var  = s2 * (1.0f / D_MODEL) - mean * mean;
        float rstd = rsqrtf(var + 1e-5f);
        float4 gg = ((const float4*)g1)[tid];
        float4 bb = ((const float4*)beta1)[tid];
        ushort4 o4;
        o4.x = f2bf((v.x - mean) * rstd * gg.x + bb.x);
        o4.y = f2bf((v.y - mean) * rstd * gg.y + bb.y);
        o4.z = f2bf((v.z - mean) * rstd * gg.z + bb.z);
        o4.w = f2bf((v.w - mean) * rstd * gg.w + bb.w);
        ((ushort4*)(h1 + (size_t)row * D_MODEL))[tid] = o4;
        return;
    }
    // ---- weight transpose ----
    const float* w; unsigned short* wt; int Kd, Nd, bx, by;
    if (id < 4096) {
        int z = id >> 10, t = id & 1023;
        w  = z == 0 ? wq  : z == 1 ? wk  : z == 2 ? wv  : wo;
        wt = z == 0 ? wqt : z == 1 ? wkt : z == 2 ? wvt : wot;
        Kd = 1024; Nd = 1024; bx = t & 31; by = t >> 5;
    } else if (id < 8192) {
        int t = id - 4096;
        w = w1; wt = w1t; Kd = 1024; Nd = 4096; bx = t & 127; by = t >> 7;
    } else {
        int t = id - 8192;
        w = w2; wt = w2t; Kd = 4096; Nd = 1024; bx = t & 31; by = t >> 5;
    }
    int n0 = bx * 32, k0 = by * 32;
    int tx = threadIdx.x & 31, ty = threadIdx.x >> 5;  // 32 x 8
#pragma unroll
    for (int i = 0; i < 4; ++i)
        tile[ty + i * 8][tx] = w[(size_t)(k0 + ty + i * 8) * Nd + n0 + tx];
    __syncthreads();
#pragma unroll
    for (int i = 0; i < 4; ++i)
        wt[(size_t)(n0 + ty + i * 8) * Kd + k0 + tx] = f2bf(tile[tx][ty + i * 8]);
}

// ---------------------------------------------------------------------------
// V transpose: v bf16 [b*1000+s][h*64+dk] -> vt bf16 [b][h*64+dk][1024] (s pad 0)
// ---------------------------------------------------------------------------
__global__ __launch_bounds__(256) void vtrans_kernel(const unsigned short* __restrict__ v,
                                                     unsigned short* __restrict__ vt) {
    __shared__ unsigned short tile[32][33];
    int b = blockIdx.z;
    int c0 = blockIdx.x * 32, s0 = blockIdx.y * 32;
    int tx = threadIdx.x, ty = threadIdx.y;
#pragma unroll
    for (int i = 0; i < 4; ++i) {
        int s = s0 + ty + i * 8;
        unsigned short val = 0;
        if (s < SEQ) val = v[((size_t)b * SEQ + s) * D_MODEL + c0 + tx];
        tile[ty + i * 8][tx] = val;
    }
    __syncthreads();
#pragma unroll
    for (int i = 0; i < 4; ++i) {
        int c = c0 + ty + i * 8;
        vt[((size_t)b * D_MODEL + c) * 1024 + s0 + tx] = tile[tx][ty + i * 8];
    }
}

// ---------------------------------------------------------------------------
// LayerNorm: x fp32 [row][1024] -> out bf16, 1 block per row
// ---------------------------------------------------------------------------
__global__ __launch_bounds__(256) void ln_kernel(const float* __restrict__ x,
                                                 const float* __restrict__ g,
                                                 const float* __restrict__ beta,
                                                 unsigned short* __restrict__ out) {
    int row = blockIdx.x, tid = threadIdx.x;
    const float4 v = ((const float4*)(x + (size_t)row * D_MODEL))[tid];
    float s  = v.x + v.y + v.z + v.w;
    float s2 = v.x * v.x + v.y * v.y + v.z * v.z + v.w * v.w;
#pragma unroll
    for (int o = 32; o > 0; o >>= 1) { s += __shfl_xor(s, o, 64); s2 += __shfl_xor(s2, o, 64); }
    __shared__ float red[8];
    int wave = tid >> 6, lane = tid & 63;
    if (lane == 0) { red[wave] = s; red[wave + 4] = s2; }
    __syncthreads();
    s  = red[0] + red[1] + red[2] + red[3];
    s2 = red[4] + red[5] + red[6] + red[7];
    float mean = s * (1.0f / D_MODEL);
    float var  = s2 * (1.0f / D_MODEL) - mean * mean;
    float rstd = rsqrtf(var + 1e-5f);
    float4 gg = ((const float4*)g)[tid];
    float4 bb = ((const float4*)beta)[tid];
    ushort4 o4;
    o4.x = f2bf((v.x - mean) * rstd * gg.x + bb.x);
    o4.y = f2bf((v.y - mean) * rstd * gg.y + bb.y);
    o4.z = f2bf((v.z - mean) * rstd * gg.z + bb.z);
    o4.w = f2bf((v.w - mean) * rstd * gg.w + bb.w);
    ((ushort4*)(out + (size_t)row * D_MODEL))[tid] = o4;
}

enum { EPI_BF16 = 0, EPI_GELU = 1, EPI_RES_F32 = 2 };

// ---------------------------------------------------------------------------
// gemm128t: R2/R4-proven 128x256 / BK=32 / SLOTS-ring / counted vmcnt
// + R7: m204 bijective XCD-chunked block remap (T1).
//
// Default dispatch round-robins consecutive block ids across the 8 XCDs
// (m09/m157), so the 4-16 column-blocks sharing one A-row-panel land on
// DIFFERENT per-XCD L2s and each refetches the panel from HBM (FFN2 FETCH
// 152.7 MB vs ~104 ideal). The remap gives each XCD a CONTIGUOUS id chunk
// (bijective for any nwg, m204): co-XCD blocks then share A-panels in L2.
// Verification signal: FETCH_SIZE must drop (FFN2 -> ~100-115 MB).
// ---------------------------------------------------------------------------
template <int EPI, bool FUSE3, int SLOTS>
__global__ __launch_bounds__(512, SLOTS == 3 ? 4 : 2) void gemm128t(
    const unsigned short* __restrict__ A,
    const unsigned short* __restrict__ Bt0,
    const unsigned short* __restrict__ Bt1,
    const unsigned short* __restrict__ Bt2,
    const float* __restrict__ bias,
    const float* __restrict__ resid,
    void* __restrict__ out0, void* out1, void* out2,
    int Mdim, int Ndim, int K) {
    constexpr int DIST = SLOTS - 1;
    __shared__ unsigned short ldsA[SLOTS][128 * 32];   // 8 KB/slot
    __shared__ unsigned short ldsB[SLOTS][256 * 32];   // 16 KB/slot
    int tid = threadIdx.x;
    int lane = tid & 63, wave = tid >> 6;
    int l15 = lane & 15, quad = lane >> 4;
    int wr = wave >> 2;
    int wc = wave & 3;

    // ---- m204 bijective XCD-chunked remap (lin -> nid) ----
    int gx = gridDim.x;
    int nwg = gx * gridDim.y;
    int lin = blockIdx.y * gx + blockIdx.x;
    int qc = nwg >> 3, rc = nwg & 7;
    int xcd = lin & 7, seq = lin >> 3;
    int nid = (xcd < rc ? xcd * (qc + 1) : rc * (qc + 1) + (xcd - rc) * qc) + seq;
    int bx = nid % gx;
    int by = nid / gx;

    int rt = by * 128;
    const unsigned short* Bt = Bt0;
    void* outp = out0;
    int ct;
    if (FUSE3) {
        int sel = bx >> 2;
        ct = (bx & 3) * 256;
        Bt   = sel == 0 ? Bt0  : (sel == 1 ? Bt1  : Bt2);
        outp = sel == 0 ? out0 : (sel == 1 ? out1 : out2);
    } else {
        ct = bx * 256;
    }

    const unsigned short* aSrc;
    {
        int p = tid >> 3, sp = (tid & 7) ^ (p & 7);
        int rrow = 2 * p + (sp >> 2), g2 = sp & 3;
        int ar = rt + rrow; if (ar >= Mdim) ar = Mdim - 1;
        aSrc = A + (size_t)ar * K + g2 * 8;
    }
    const unsigned short* bSrc[2];
#pragma unroll
    for (int j = 0; j < 2; ++j) {
        int gl = tid + j * 512;
        int p = gl >> 3, sp = (gl & 7) ^ (p & 7);
        int rrow = 2 * p + (sp >> 2), g2 = sp & 3;
        bSrc[j] = Bt + (size_t)(ct + rrow) * K + g2 * 8;
    }
    auto stage = [&](int kt, int sl) {
        gload_lds16(aSrc + (size_t)kt * 32, (char*)ldsA[sl] + wave * 1024);
        gload_lds16(bSrc[0] + (size_t)kt * 32, (char*)ldsB[sl] + wave * 1024);
        gload_lds16(bSrc[1] + (size_t)kt * 32, (char*)ldsB[sl] + 8192 + wave * 1024);
    };

    int lh = l15 >> 1;
    int mslot = (quad + ((l15 & 1) << 2)) ^ lh;
    unsigned aOff = (unsigned)((wr * 32 + lh) * 128 + mslot * 16);
    unsigned bOff = (unsigned)((wc * 32 + lh) * 128 + mslot * 16);

    f32x4_t acc[4][4] = {};
    int NT = K >> 5;

#pragma unroll
    for (int d = 0; d < DIST; ++d) stage(d, d);

    int scur = 0, spre = DIST;
    for (int t = 0; t < NT; ++t) {
        int rem = NT - 1 - t;
        if constexpr (SLOTS == 4) {
            if (rem >= 2)      asm volatile("s_waitcnt vmcnt(6)" ::: "memory");
            else if (rem == 1) asm volatile("s_waitcnt vmcnt(3)" ::: "memory");
            else               asm volatile("s_waitcnt vmcnt(0)" ::: "memory");
        } else {
            if (rem >= 1)      asm volatile("s_waitcnt vmcnt(3)" ::: "memory");
            else               asm volatile("s_waitcnt vmcnt(0)" ::: "memory");
        }
        __builtin_amdgcn_s_barrier();
        const char* la = (const char*)ldsA[scur];
        const char* lb = (const char*)ldsB[scur];
        short8_t af[4], bfv[4];
#pragma unroll
        for (int mi = 0; mi < 4; ++mi)
            af[mi] = *(const short8_t*)(la + aOff + mi * 1024);
#pragma unroll
        for (int ni = 0; ni < 4; ++ni)
            bfv[ni] = *(const short8_t*)(lb + bOff + ni * 1024);
        if (t + DIST < NT) stage(t + DIST, spre);
        __builtin_amdgcn_s_setprio(1);
#pragma unroll
        for (int mi = 0; mi < 4; ++mi)
#pragma unroll
            for (int ni = 0; ni < 4; ++ni)
                acc[mi][ni] = mfma_bf16(af[mi], bfv[ni], acc[mi][ni]);
        __builtin_amdgcn_s_setprio(0);
        scur = (scur == SLOTS - 1) ? 0 : scur + 1;
        spre = (spre == SLOTS - 1) ? 0 : spre + 1;
    }

    float bias_c[4];
    if (EPI != EPI_BF16) {
#pragma unroll
        for (int ni = 0; ni < 4; ++ni) bias_c[ni] = bias[ct + wc * 64 + ni * 16 + l15];
    }

    // epilogue: C/D layout col=lane&15, row=quad*4+reg
#pragma unroll
    for (int mi = 0; mi < 4; ++mi) {
#pragma unroll
        for (int r = 0; r < 4; ++r) {
            int grow = rt + wr * 64 + mi * 16 + quad * 4 + r;
            if (grow >= Mdim) continue;
#pragma unroll
            for (int ni = 0; ni < 4; ++ni) {
                int gcol = ct + wc * 64 + ni * 16 + l15;
                float v = acc[mi][ni][r];
                size_t idx = (size_t)grow * Ndim + gcol;
                if (EPI == EPI_BF16) {
                    ((unsigned short*)outp)[idx] = f2bf(v);
                } else if (EPI == EPI_GELU) {
                    v += bias_c[ni];
                    ((unsigned short*)outp)[idx] = f2bf(gelu_fast(v));
                } else {
                    v += bias_c[ni] + resid[idx];
                    ((float*)outp)[idx] = v;
                }
            }
        }
    }
}

// ---------------------------------------------------------------------------
// Flash attention v3: triangle-balanced + double-buffered DMA staging.
// (unchanged — proven)
// ---------------------------------------------------------------------------
__global__ __launch_bounds__(256) void attn_kernel(
    const unsigned short* __restrict__ q,
    const unsigned short* __restrict__ k,
    const unsigned short* __restrict__ vt,
    unsigned short* __restrict__ att) {
    int p = blockIdx.x, h = blockIdx.y, b = blockIdx.z;
    int tid = threadIdx.x, lane = tid & 63, wave = tid >> 6;
    int l15 = lane & 15, quad = lane >> 4;
    __shared__ unsigned short kt_lds[2][64 * 64];
    __shared__ unsigned short vt_lds[2][64 * 64];
    __shared__ unsigned short p_lds[4][32 * 64];
    unsigned short* pw = p_lds[wave];

    const int qtA = p, qtB = 7 - p;
    const int tA = 2 * qtA + 2, tB = 2 * qtB + 2, total = tA + tB;  // == 18

    short8_t aq[2][2][2];  // [phase][g][kc]
#pragma unroll
    for (int ph = 0; ph < 2; ++ph) {
        int qw = (ph ? qtB : qtA) * 128 + wave * 32;
#pragma unroll
        for (int g = 0; g < 2; ++g) {
            int qr = qw + g * 16 + l15; if (qr > SEQ - 1) qr = SEQ - 1;
            const unsigned short* qp = q + ((size_t)(b * SEQ + qr)) * D_MODEL + h * 64 + quad * 8;
            aq[ph][g][0] = *(const short8_t*)qp;
            aq[ph][g][1] = *(const short8_t*)(qp + 32);
        }
    }

    f32x4_t o[2][4] = {};
    float m_run[2] = {-3.0e38f, -3.0e38f};
    float l_run[2] = {0.f, 0.f};

    auto stage = [&](int kt, int bufi) {
#pragma unroll
        for (int i = 0; i < 2; ++i) {
            int g2 = tid + i * 256;
            int row = g2 >> 3, cp = g2 & 7;
            int c = cp ^ (row & 7);
            int key = kt * 64 + row; int keyc = key < SEQ ? key : SEQ - 1;
            gload_lds16(k + ((size_t)(b * SEQ + keyc)) * D_MODEL + h * 64 + c * 8,
                        (char*)kt_lds[bufi] + (size_t)(wave * 64 + i * 256) * 16);
            gload_lds16(vt + ((size_t)((b * N_HEADS + h) * 64 + row)) * 1024 + kt * 64 + c * 8,
                        (char*)vt_lds[bufi] + (size_t)(wave * 64 + i * 256) * 16);
        }
    };

    auto flush = [&](int qt) {
#pragma unroll
        for (int g = 0; g < 2; ++g) {
            float linv = __builtin_amdgcn_rcpf(l_run[g]);
#pragma unroll
            for (int r = 0; r < 4; ++r) {
                float nr = __shfl(linv, quad * 4 + r, 64);
                int qg = qt * 128 + wave * 32 + g * 16 + quad * 4 + r;
                if (qg >= SEQ) continue;
#pragma unroll
                for (int db = 0; db < 4; ++db)
                    att[((size_t)(b * SEQ + qg)) * D_MODEL + h * 64 + db * 16 + l15] =
                        f2bf(o[g][db][r] * nr);
            }
        }
#pragma unroll
        for (int g = 0; g < 2; ++g) {
            m_run[g] = -3.0e38f; l_run[g] = 0.f;
#pragma unroll
            for (int db = 0; db < 4; ++db) o[g][db] = f32x4_t{0.f, 0.f, 0.f, 0.f};
        }
    };

    stage(0, 0);

    for (int i = 0; i < total; ++i) {
        int bufi = i & 1;
        __syncthreads();
        if (i + 1 < total) {
            int nkt = (i + 1 < tA) ? (i + 1) : (i + 1 - tA);
            stage(nkt, bufi ^ 1);
        }
        int phase = (i < tA) ? 0 : 1;
        int kt = (i < tA) ? i : i - tA;
        int qt = phase ? qtB : qtA;
        int qw = qt * 128 + wave * 32;
        const unsigned short* kl = kt_lds[bufi];
        const unsigned short* vl = vt_lds[bufi];

        if (kt * 64 <= qw + 31) {
            short8_t kf[4][2];
#pragma unroll
            for (int nb = 0; nb < 4; ++nb)
#pragma unroll
                for (int kc = 0; kc < 2; ++kc) {
                    int row = nb * 16 + l15;
                    kf[nb][kc] = *(const short8_t*)(kl + (row * 8 + ((kc * 4 + quad) ^ (row & 7))) * 8);
                }

            bool gact[2];
#pragma unroll
            for (int g = 0; g < 2; ++g) {
                gact[g] = (kt * 64 <= qw + g * 16 + 15);
                if (!gact[g]) continue;
                f32x4_t s[4] = {};
#pragma unroll
                for (int nb = 0; nb < 4; ++nb)
#pragma unroll
                    for (int kc = 0; kc < 2; ++kc)
                        s[nb] = mfma_bf16(kf[nb][kc], aq[phase][g][kc], s[nb]);
                int qrow = qw + g * 16 + l15;
                float sc[4][4];
#pragma unroll
                for (int nb = 0; nb < 4; ++nb)
#pragma unroll
                    for (int r = 0; r < 4; ++r) {
                        int key = kt * 64 + nb * 16 + quad * 4 + r;
                        float v = s[nb][r] * 0.125f;
                        sc[nb][r] = (key <= qrow) ? v : -1e30f;
                    }
                float mx = sc[0][0];
#pragma unroll
                for (int nb = 0; nb < 4; ++nb)
#pragma unroll
                    for (int r = 0; r < 4; ++r) mx = fmaxf(mx, sc[nb][r]);
                mx = fmaxf(mx, __shfl_xor(mx, 16, 64));
                mx = fmaxf(mx, __shfl_xor(mx, 32, 64));
                float mnew = fmaxf(m_run[g], mx);
                float alpha = __expf(m_run[g] - mnew);
                m_run[g] = mnew;
                float rs = 0.f;
#pragma unroll
                for (int nb = 0; nb < 4; ++nb)
#pragma unroll
                    for (int r = 0; r < 4; ++r) {
                        float pv = __expf(sc[nb][r] - mnew);
                        sc[nb][r] = pv;
                        rs += pv;
                    }
                rs += __shfl_xor(rs, 16, 64);
                rs += __shfl_xor(rs, 32, 64);
                l_run[g] = l_run[g] * alpha + rs;
#pragma unroll
                for (int r = 0; r < 4; ++r) {
                    float a = __shfl(alpha, quad * 4 + r, 64);
#pragma unroll
                    for (int db = 0; db < 4; ++db) o[g][db][r] *= a;
                }
#pragma unroll
                for (int nb = 0; nb < 4; ++nb) {
                    unsigned long long pv =
                        (unsigned long long)f2bf(sc[nb][0]) |
                        ((unsigned long long)f2bf(sc[nb][1]) << 16) |
                        ((unsigned long long)f2bf(sc[nb][2]) << 32) |
                        ((unsigned long long)f2bf(sc[nb][3]) << 48);
                    int chunk = (4 * nb + quad) ^ ((l15 & 7) << 1);
                    *(unsigned long long*)(pw + (g * 16 + l15) * 64 + chunk * 4) = pv;
                }
            }
            asm volatile("s_waitcnt lgkmcnt(0)" ::: "memory");

            short8_t vf[4][2];
#pragma unroll
            for (int db = 0; db < 4; ++db)
#pragma unroll
                for (int kc = 0; kc < 2; ++kc) {
                    int row = db * 16 + l15;
                    vf[db][kc] = *(const short8_t*)(vl + (row * 8 + ((kc * 4 + quad) ^ (row & 7))) * 8);
                }
#pragma unroll
            for (int g = 0; g < 2; ++g) {
                if (!gact[g]) continue;
                short8_t ap[2];
#pragma unroll
                for (int kc = 0; kc < 2; ++kc)
                    ap[kc] = *(const short8_t*)(pw + (g * 16 + l15) * 64 +
                                                ((kc * 4 + quad) ^ (l15 & 7)) * 8);
#pragma unroll
                for (int db = 0; db < 4; ++db)
#pragma unroll
                    for (int kc = 0; kc < 2; ++kc)
                        o[g][db] = mfma_bf16(ap[kc], vf[db][kc], o[g][db]);
            }
        }

        if (i == tA - 1) flush(qtA);
    }
    flush(qtB);
}

// ---------------------------------------------------------------------------
extern "C" void kernel_launch(void* const* d_in, const int* in_sizes, int n_in,
                              void* d_out, int out_size, void* d_ws, size_t ws_size,
                              hipStream_t stream) {
    const float* x     = (const float*)d_in[0];
    const float* wq    = (const float*)d_in[1];
    const float* wk    = (const float*)d_in[2];
    const float* wv    = (const float*)d_in[3];
    const float* wo    = (const float*)d_in[4];
    const float* bo    = (const float*)d_in[5];
    const float* w1    = (const float*)d_in[6];
    const float* b1    = (const float*)d_in[7];
    const float* w2    = (const float*)d_in[8];
    const float* b2    = (const float*)d_in[9];
    const float* g1    = (const float*)d_in[10];
    const float* beta1 = (const float*)d_in[11];
    const float* g2    = (const float*)d_in[12];
    const float* beta2 = (const float*)d_in[13];
    float* out = (float*)d_out;
    char* ws = (char*)d_ws;

    const size_t SZ_MD_BF16 = (size_t)M_TOK * D_MODEL * 2;  // 16,384,000
    unsigned short* h1  = (unsigned short*)(ws);                       // also h2 (alias)
    unsigned short* qb  = (unsigned short*)(ws + SZ_MD_BF16);
    unsigned short* kb  = (unsigned short*)(ws + 2 * SZ_MD_BF16);
    unsigned short* vb  = (unsigned short*)(ws + 3 * SZ_MD_BF16);
    unsigned short* atb = (unsigned short*)(ws + 4 * SZ_MD_BF16);
    unsigned short* ffb = qb;                                          // alias: q..att dead after WO
    size_t off = 5 * SZ_MD_BF16;
    unsigned short* vtb = (unsigned short*)(ws + off); off += (size_t)BATCH * D_MODEL * 1024 * 2; // 16.78MB
    float* x1 = (float*)(ws + off); off += (size_t)M_TOK * D_MODEL * 4;
    unsigned short* wqt = (unsigned short*)(ws + off); off += (size_t)D_MODEL * D_MODEL * 2;
    unsigned short* wkt = (unsigned short*)(ws + off); off += (size_t)D_MODEL * D_MODEL * 2;
    unsigned short* wvt = (unsigned short*)(ws + off); off += (size_t)D_MODEL * D_MODEL * 2;
    unsigned short* wot = (unsigned short*)(ws + off); off += (size_t)D_MODEL * D_MODEL * 2;
    unsigned short* w1t = (unsigned short*)(ws + off); off += (size_t)D_MODEL * D_FF * 2;
    unsigned short* w2t = (unsigned short*)(ws + off); off += (size_t)D_MODEL * D_FF * 2;

    // all weight transposes + LN1 in one launch
    prep_kernel<<<12288 + M_TOK, 256, 0, stream>>>(
        wq, wk, wv, wo, w1, w2, wqt, wkt, wvt, wot, w1t, w2t, x, g1, beta1, h1);

    const int MT128 = (M_TOK + 127) / 128;  // 63

    // QKV fused: 12 x 63 = 756 blocks, SLOTS=3 (2 blocks/CU) + XCD chunking
    gemm128t<EPI_BF16, true, 3><<<dim3(12, MT128), 512, 0, stream>>>(
        h1, wqt, wkt, wvt, nullptr, nullptr, qb, kb, vb, M_TOK, D_MODEL, D_MODEL);

    dim3 tb(32, 8);
    vtrans_kernel<<<dim3(32, 32, 8), tb, 0, stream>>>(vb, vtb);

    attn_kernel<<<dim3(4, N_HEADS, BATCH), 256, 0, stream>>>(qb, kb, vtb, atb);

    // WO: 4 x 63 = 252 blocks, SLOTS=4 + XCD chunking
    gemm128t<EPI_RES_F32, false, 4><<<dim3(4, MT128), 512, 0, stream>>>(
        atb, wot, nullptr, nullptr, bo, x, x1, nullptr, nullptr, M_TOK, D_MODEL, D_MODEL);

    ln_kernel<<<M_TOK, 256, 0, stream>>>(x1, g2, beta2, h1);  // h2 aliases h1

    // FFN1: 16 x 63 = 1008 blocks, SLOTS=3 (2 blocks/CU) + XCD chunking
    gemm128t<EPI_GELU, false, 3><<<dim3(16, MT128), 512, 0, stream>>>(
        h1, w1t, nullptr, nullptr, b1, nullptr, ffb, nullptr, nullptr, M_TOK, D_FF, D_MODEL);

    // FFN2: 4 x 63 = 252 blocks, SLOTS=4 + XCD chunking (K=4096)
    gemm128t<EPI_RES_F32, false, 4><<<dim3(4, MT128), 512, 0, stream>>>(
        ffb, w2t, nullptr, nullptr, b2, x1, out, nullptr, nullptr, M_TOK, D_MODEL, D_FF);
}